// Round 1
// baseline (2163.264 us; speedup 1.0000x reference)
//
#include <hip/hip_runtime.h>
#include <math.h>

#define NGRAPH 1024
#define NN     256      // nodes per graph (layer-1)
#define NE     2048     // edges per graph
#define EMB    39       // input feature dim
#define HD     64       // hidden dim
#define STRIDE 65       // node-major LDS row stride (pad +1: all patterns <=2-way bank aliased)
#define NT     512      // threads per block (8 waves)

// k sizes: k1=ceil(0.8*256)=205, k2=ceil(double(0.8)*205)=164 (product rounds to exactly 164.0),
// k3=ceil(0.8*164)=132  -- verified against double-precision semantics of math.ceil(RATIO*n).
#define K1 205
#define K2 164
#define K3 132

#define BUF_F (NN * STRIDE)   // 16640 floats per ping-pong buffer

// LDS budget (bytes):
//  bufA+bufB: 2*16640*4 = 133120
//  ecoef: 2048*4 = 8192 ; deg/dinv/score/sctmp: 4*256*4 = 4096 ; feats 512
//  redmax/redsum: 2*512*4 = 4096 ; pn 256 ; mlp1 256 ; mlp2 128
//  epack0/epack: 2*2048*2 = 8192 ; nodemap/rnk: 2*256*2 = 1024
//  total = 159872  (< 163840 LDS/CU on gfx950) -> 1 block/CU
#define SMEM_BYTES 159872

__global__ __launch_bounds__(NT, 2) void gnn_pool_kernel(
    const float* __restrict__ gx, const int* __restrict__ gedge,
    const float* __restrict__ W1, const float* __restrict__ b1, const float* __restrict__ p1,
    const float* __restrict__ W2, const float* __restrict__ b2, const float* __restrict__ p2,
    const float* __restrict__ W3, const float* __restrict__ b3, const float* __restrict__ p3,
    const float* __restrict__ lW1, const float* __restrict__ lb1,
    const float* __restrict__ lW2, const float* __restrict__ lb2,
    const float* __restrict__ lW3, const float* __restrict__ lb3,
    float* __restrict__ gout)
{
    extern __shared__ __align__(16) char smem_raw[];
    float* bufA   = (float*)smem_raw;            // 16640
    float* bufB   = bufA + BUF_F;                // 16640
    float* ecoef  = bufB + BUF_F;                // 2048
    float* deg    = ecoef + NE;                  // 256
    float* dinv   = deg + NN;                    // 256
    float* score  = dinv + NN;                   // 256
    float* sctmp  = score + NN;                  // 256
    float* feats  = sctmp + NN;                  // 128
    float* redmax = feats + 2 * HD;              // 8*64
    float* redsum = redmax + 8 * HD;             // 8*64
    float* pn     = redsum + 8 * HD;             // 64
    float* mlp1   = pn + HD;                     // 64
    float* mlp2   = mlp1 + HD;                   // 32
    unsigned short* epack0 = (unsigned short*)(mlp2 + 32); // 2048
    unsigned short* epack  = epack0 + NE;                  // 2048
    short* nodemap = (short*)(epack + NE);                 // 256 (orig id -> current id, -1 dropped)
    short* rnk     = nodemap + NN;                         // 256

    const int tid = threadIdx.x;
    const int b   = blockIdx.x;

    // ---- load inputs into LDS ----
    {
        const int* eb = gedge + (size_t)b * 2 * NE;
        for (int e = tid; e < NE; e += NT) {
            int s0 = eb[e];
            int d0 = eb[NE + e];
            epack0[e] = (unsigned short)((s0 & 0xFF) | ((d0 & 0xFF) << 8));
        }
        const float* xb = gx + (size_t)b * NN * EMB;
        for (int i = tid; i < NN * EMB; i += NT) {
            bufA[(i / EMB) * STRIDE + (i % EMB)] = xb[i];
        }
        if (tid < NN) nodemap[tid] = (short)tid;
        if (tid < 2 * HD) feats[tid] = 0.f;
    }
    __syncthreads();

    float* cur = bufA;   // current node features (n x fin)
    float* nxt = bufB;   // scratch: h, then pooled output
    int n = NN;
    int fin = EMB;
    const float* Ws[3] = {W1, W2, W3};
    const float* bs[3] = {b1, b2, b3};
    const float* ps[3] = {p1, p2, p3};
    const int    ks[3] = {K1, K2, K3};

    for (int L = 0; L < 3; L++) {
        const float* W  = Ws[L];
        const float* bb = bs[L];
        const float* pp = ps[L];
        const int k = ks[L];

        // P0: init deg; wave 0 computes normalized projection vector pn = p/||p||
        if (tid < n) deg[tid] = 1.0f;
        if (tid < HD) {
            float pv = pp[tid];
            float s2 = pv * pv;
            #pragma unroll
            for (int off = 32; off >= 1; off >>= 1) s2 += __shfl_xor(s2, off, 64);
            pn[tid] = pv * rsqrtf(s2);
        }
        __syncthreads();

        // P1: remap original edges through cumulative map; accumulate degree
        for (int e = tid; e < NE; e += NT) {
            int pk0 = epack0[e];
            int s = nodemap[pk0 & 0xFF];
            int d = nodemap[pk0 >> 8];
            bool v = (s >= 0) && (d >= 0);
            epack[e] = v ? (unsigned short)(s | (d << 8)) : (unsigned short)0;
            ecoef[e] = v ? 1.f : 0.f;   // validity carrier; coef filled in P3
            if (v) atomicAdd(&deg[d], 1.0f);
        }
        __syncthreads();

        // P2: dinv = rsqrt(deg)
        if (tid < n) dinv[tid] = rsqrtf(deg[tid]);
        __syncthreads();

        // P3: edge coefficients + dense h = x @ W  (node-split: 2 threads/node, 32 outputs each)
        for (int e = tid; e < NE; e += NT) {
            if (ecoef[e] != 0.f) {
                int pk = epack[e];
                ecoef[e] = dinv[pk & 0xFF] * dinv[pk >> 8];
            }
        }
        {
            int node = tid & (NN - 1);
            int half = __builtin_amdgcn_readfirstlane(tid >> 8); // wave-uniform 0/1 -> scalar W loads
            if (node < n) {
                float acc[32];
                #pragma unroll
                for (int j = 0; j < 32; j++) acc[j] = 0.f;
                const float* Wp = W + half * 32;
                const float* xrow = cur + node * STRIDE;
                for (int kk = 0; kk < fin; kk++) {
                    float xv = xrow[kk];
                    #pragma unroll
                    for (int j = 0; j < 32; j++) acc[j] = fmaf(xv, Wp[kk * HD + j], acc[j]);
                }
                float* hrow = nxt + node * STRIDE + half * 32;
                #pragma unroll
                for (int j = 0; j < 32; j++) hrow[j] = acc[j];
            }
        }
        __syncthreads();

        // P4: zero agg region (cur is dead as x-input now) and score partials
        for (int i = tid; i < n * HD; i += NT) cur[(i >> 6) * STRIDE + (i & 63)] = 0.f;
        if (tid < n) sctmp[tid] = 0.f;
        __syncthreads();

        // P5: scatter-aggregate: one wave per edge, lane = feature.
        // addr = d*65 + lane -> bank (d+lane)%32: exactly 2-way, free.
        {
            int lane = tid & 63;
            int wv = tid >> 6;  // 0..7
            for (int e = wv; e < NE; e += 8) {
                float c = ecoef[e];            // broadcast read; 0 => invalid (valid coef > 0 always)
                if (c != 0.f) {
                    int pk = epack[e];
                    float hv = nxt[(pk & 0xFF) * STRIDE + lane];
                    atomicAdd(&cur[(pk >> 8) * STRIDE + lane], hv * c);
                }
            }
        }
        __syncthreads();

        // P6: out = relu(agg + h/deg + b); accumulate score dot-product partials
        {
            int node = tid & (NN - 1);
            int half = __builtin_amdgcn_readfirstlane(tid >> 8);
            if (node < n) {
                float inv = 1.0f / deg[node];
                int jo = half * 32;
                float sc = 0.f;
                float* crow = cur + node * STRIDE + jo;
                const float* hrow = nxt + node * STRIDE + jo;
                #pragma unroll
                for (int j = 0; j < 32; j++) {
                    float o = crow[j] + hrow[j] * inv + bb[jo + j];
                    o = fmaxf(o, 0.f);
                    crow[j] = o;
                    sc = fmaf(o, pn[jo + j], sc);
                }
                atomicAdd(&sctmp[node], sc);
            }
        }
        __syncthreads();

        // P7: score = tanh(x . p/||p||)
        if (tid < n) score[tid] = tanhf(sctmp[tid]);
        __syncthreads();

        // P8: rank by counting (stable desc order == jax.lax.top_k tie-break)
        if (tid < n) {
            float si = score[tid];
            int r = 0;
            for (int j = 0; j < n; j++) {
                float sj = score[j];              // same address across lanes -> LDS broadcast
                r += (sj > si) || (sj == si && j < tid);
            }
            rnk[tid] = (short)r;
        }
        __syncthreads();

        // P9: pool selected rows (scaled by tanh score) into nxt; compose cumulative node map
        if (tid < n) {
            int r = rnk[tid];
            if (r < k) {
                float v = score[tid];
                const float* srow = cur + tid * STRIDE;
                float* drow = nxt + r * STRIDE;
                #pragma unroll 8
                for (int j = 0; j < HD; j++) drow[j] = srow[j] * v;
            }
        }
        if (tid < NN) {
            int m = nodemap[tid];
            if (m >= 0) {
                int r = rnk[m];
                nodemap[tid] = (short)((r < k) ? r : -1);
            }
        }
        __syncthreads();

        // P10: readout (max & mean over k pooled rows), accumulate into feats
        {
            int f = tid & 63;
            int q = tid >> 6;
            float mx = -3.0e38f, sm = 0.f;
            for (int i = q; i < k; i += 8) {
                float v = nxt[i * STRIDE + f];
                mx = fmaxf(mx, v);
                sm += v;
            }
            redmax[q * 64 + f] = mx;
            redsum[q * 64 + f] = sm;
        }
        __syncthreads();
        if (tid < 64) {
            float mx = redmax[tid], sm = redsum[tid];
            #pragma unroll
            for (int q = 1; q < 8; q++) {
                mx = fmaxf(mx, redmax[q * 64 + tid]);
                sm += redsum[q * 64 + tid];
            }
            feats[tid] += mx;
            feats[64 + tid] += sm / (float)k;
        }
        __syncthreads();

        // ping-pong
        float* t = cur; cur = nxt; nxt = t;
        n = k;
        fin = HD;
    }

    // ---- final MLP: 128 -> 64 -> 32 -> 1, sigmoid ----
    if (tid < 64) {
        float a = lb1[tid];
        for (int i = 0; i < 2 * HD; i++) a = fmaf(feats[i], lW1[i * 64 + tid], a);
        mlp1[tid] = fmaxf(a, 0.f);
    }
    __syncthreads();
    if (tid < 32) {
        float a = lb2[tid];
        for (int i = 0; i < 64; i++) a = fmaf(mlp1[i], lW2[i * 32 + tid], a);
        mlp2[tid] = fmaxf(a, 0.f);
    }
    __syncthreads();
    if (tid == 0) {
        float a = lb3[0];
        for (int i = 0; i < 32; i++) a = fmaf(mlp2[i], lW3[i], a);
        gout[b] = 1.0f / (1.0f + expf(-a));
    }
}

extern "C" void kernel_launch(void* const* d_in, const int* in_sizes, int n_in,
                              void* d_out, int out_size, void* d_ws, size_t ws_size,
                              hipStream_t stream) {
    const float* gx    = (const float*)d_in[0];
    const int*   gedge = (const int*)d_in[1];   // int32 (JAX x64 disabled)
    const float* W1 = (const float*)d_in[2];
    const float* b1 = (const float*)d_in[3];
    const float* p1 = (const float*)d_in[4];
    const float* W2 = (const float*)d_in[5];
    const float* b2 = (const float*)d_in[6];
    const float* p2 = (const float*)d_in[7];
    const float* W3 = (const float*)d_in[8];
    const float* b3 = (const float*)d_in[9];
    const float* p3 = (const float*)d_in[10];
    const float* lW1 = (const float*)d_in[11];
    const float* lb1 = (const float*)d_in[12];
    const float* lW2 = (const float*)d_in[13];
    const float* lb2 = (const float*)d_in[14];
    const float* lW3 = (const float*)d_in[15];
    const float* lb3 = (const float*)d_in[16];
    float* gout = (float*)d_out;

    // opt-in to >64KB dynamic LDS (160KB/CU on gfx950); idempotent, capture-safe host call
    (void)hipFuncSetAttribute((const void*)gnn_pool_kernel,
                              hipFuncAttributeMaxDynamicSharedMemorySize, SMEM_BYTES);

    gnn_pool_kernel<<<NGRAPH, NT, SMEM_BYTES, stream>>>(
        gx, gedge, W1, b1, p1, W2, b2, p2, W3, b3, p3,
        lW1, lb1, lW2, lb2, lW3, lb3, gout);
}